// Round 8
// baseline (196.057 us; speedup 1.0000x reference)
//
#include <hip/hip_runtime.h>
#include <math.h>

// x,y: [B, C] fp32; u: scalar fp32.
#define B_ROWS 65536
#define C_COLS 1024
#define NBLOCKS 2048
#define WPB 4
#define NWAVES (NBLOCKS * WPB)   // 8192 waves
#define RPW (B_ROWS / NWAVES)    // 8 rows per wave

typedef float v4f __attribute__((ext_vector_type(4)));

// VGPR/BW history: 32->2.5, 60->1.43, 80->1.41, ~128->~6 TB/s. The compiler's
// scheduler serializes source-level double buffers to minimize register
// pressure whenever the fused tail is present (rounds 5-7). Fix: the loads
// are inline-asm volatile (mutually ordered, scheduler can't sink them), and
// consumption is gated by counted s_waitcnt vmcnt(8) + sched_barrier(0)
// (rule #18: compute hoists past asm waitcnt without the sched_barrier).
// VMEM retires in order, so vmcnt(8) after issuing 8 new loads == "previous
// row's 8 loads have landed". Ping-pong A/B buffers, no copy-swap.

#define ISSUE(BX, BY)                                                     \
  do {                                                                    \
    asm volatile("global_load_dwordx4 %0, %1, off"                        \
                 : "=v"(BX[0]) : "v"(xa) : "memory");                     \
    asm volatile("global_load_dwordx4 %0, %1, off offset:1024"            \
                 : "=v"(BX[1]) : "v"(xa) : "memory");                     \
    asm volatile("global_load_dwordx4 %0, %1, off offset:2048"            \
                 : "=v"(BX[2]) : "v"(xa) : "memory");                     \
    asm volatile("global_load_dwordx4 %0, %1, off offset:3072"            \
                 : "=v"(BX[3]) : "v"(xa) : "memory");                     \
    asm volatile("global_load_dwordx4 %0, %1, off"                        \
                 : "=v"(BY[0]) : "v"(ya) : "memory");                     \
    asm volatile("global_load_dwordx4 %0, %1, off offset:1024"            \
                 : "=v"(BY[1]) : "v"(ya) : "memory");                     \
    asm volatile("global_load_dwordx4 %0, %1, off offset:2048"            \
                 : "=v"(BY[2]) : "v"(ya) : "memory");                     \
    asm volatile("global_load_dwordx4 %0, %1, off offset:3072"            \
                 : "=v"(BY[3]) : "v"(ya) : "memory");                     \
    xa += 4096; ya += 4096;                                               \
  } while (0)

#define WAITV(N)                                                          \
  do {                                                                    \
    asm volatile("s_waitcnt vmcnt(" #N ")" ::: "memory");                 \
    __builtin_amdgcn_sched_barrier(0);                                    \
  } while (0)

#define COMP(BX, BY, R)                                                   \
  do {                                                                    \
    float se_l = 0.f, sxy_l = 0.f, sy_l = 0.f;                            \
    _Pragma("unroll")                                                     \
    for (int i = 0; i < 4; ++i) {                                         \
      se_l  += __expf(BX[i].x) + __expf(BX[i].y) +                        \
               __expf(BX[i].z) + __expf(BX[i].w);                         \
      sxy_l += BX[i].x * BY[i].x + BX[i].y * BY[i].y +                    \
               BX[i].z * BY[i].z + BX[i].w * BY[i].w;                     \
      sy_l  += BY[i].x + BY[i].y + BY[i].z + BY[i].w;                     \
    }                                                                     \
    se[R] = se_l; sxy[R] = sxy_l;                                         \
    choice |= (__any(sy_l > 0.f) ? 1u : 0u) << (R);                       \
  } while (0)

__global__ __launch_bounds__(256) void mnl_fused_kernel(
    const float* __restrict__ x,
    const float* __restrict__ y,
    const float* __restrict__ u,
    float* __restrict__ partial,
    unsigned* __restrict__ cnt,     // zeroed by memset node each call
    float* __restrict__ out) {
  const int wave = threadIdx.x >> 6;
  const int lane = threadIdx.x & 63;
  const int gwave = blockIdx.x * WPB + wave;
  const long long row0 = (long long)gwave * RPW;
  const float u0 = u[0];

  // per-lane byte addresses; each row is 4096 B, each lane owns 4x16B chunks
  const char* xa = (const char*)x + row0 * 4096 + lane * 16;
  const char* ya = (const char*)y + row0 * 4096 + lane * 16;

  float se[RPW], sxy[RPW];
  unsigned choice = 0;

  v4f Ax[4], Ay[4], Bx[4], By[4];

  ISSUE(Ax, Ay);                     // row 0 in flight (8 loads)

#pragma unroll
  for (int rr = 0; rr < RPW; rr += 2) {
    if (rr + 1 < RPW) { ISSUE(Bx, By); WAITV(8); }   // row rr+1 in flight
    else              { WAITV(0); }
    COMP(Ax, Ay, rr);                                // consume row rr

    if (rr + 2 < RPW) { ISSUE(Ax, Ay); WAITV(8); }   // row rr+2 in flight
    else              { WAITV(0); }
    COMP(Bx, By, rr + 1);                            // consume row rr+1
  }

  // Batched butterflies: 8 rows x 2 vars = 16 independent DS ops per step.
#pragma unroll
  for (int off = 1; off < 64; off <<= 1) {
#pragma unroll
    for (int r = 0; r < RPW; ++r) {
      se[r]  += __shfl_xor(se[r],  off, 64);
      sxy[r] += __shfl_xor(sxy[r], off, 64);
    }
  }

  // 8 independent transcendental tails; result uniform across lanes.
  float acc = 0.f;
#pragma unroll
  for (int r = 0; r < RPW; ++r) {
    const float lse = __logf(se[r]);                             // logsumexp
    const float a = fmaxf(u0, lse);
    const float logden = a + log1pf(__expf(-fabsf(u0 - lse)));   // logaddexp
    const float s = ((choice >> r) & 1u) ? sxy[r] : u0;
    acc += s - logden;
  }

  __shared__ float sh[WPB];
  __shared__ bool is_last;
  if (lane == 0) sh[wave] = acc;
  __syncthreads();
  if (threadIdx.x == 0) {
    partial[blockIdx.x] = sh[0] + sh[1] + sh[2] + sh[3];
    __threadfence();                          // release partial before ticket
    const unsigned old = atomicAdd(cnt, 1u);  // device-scope by default
    is_last = (old == NBLOCKS - 1);
  }
  __syncthreads();

  if (is_last) {
    __threadfence();                          // acquire all partials
    const volatile float* vp = partial;       // bypass stale L1
    float a2 = 0.f;
    for (int i = threadIdx.x; i < NBLOCKS; i += 256) a2 += vp[i];
#pragma unroll
    for (int off = 1; off < 64; off <<= 1) a2 += __shfl_xor(a2, off, 64);

    __shared__ float sh2[WPB];
    if (lane == 0) sh2[wave] = a2;
    __syncthreads();
    if (threadIdx.x == 0) {
      const float t = sh2[0] + sh2[1] + sh2[2] + sh2[3];
      const float scale = 1.0f / (2.302585092994046f * (float)B_ROWS);
      out[0] = -t * scale;   // -mean( (s - logden)/ln10 )
    }
  }
}

extern "C" void kernel_launch(void* const* d_in, const int* in_sizes, int n_in,
                              void* d_out, int out_size, void* d_ws, size_t ws_size,
                              hipStream_t stream) {
  const float* x = (const float*)d_in[0];
  const float* y = (const float*)d_in[1];
  const float* u = (const float*)d_in[2];
  float* out = (float*)d_out;
  float* partial = (float*)d_ws;                       // 2048 floats = 8 KiB
  unsigned* cnt = (unsigned*)((char*)d_ws + NBLOCKS * sizeof(float));

  // Counter must start at 0 every call (ws is poisoned to 0xAA once and
  // never re-poisoned). 4-byte memset node: ~1us, graph-capturable.
  hipMemsetAsync(cnt, 0, sizeof(unsigned), stream);

  mnl_fused_kernel<<<NBLOCKS, 256, 0, stream>>>(x, y, u, partial, cnt, out);
}

// Round 9
// 93.162 us; speedup vs baseline: 2.1045x; 2.1045x over previous
//
#include <hip/hip_runtime.h>
#include <math.h>

// x,y: [B, C] fp32; u: scalar fp32.
#define B_ROWS 65536
#define C_COLS 1024
#define NBLOCKS 2048
#define WAVES_PER_BLOCK 4
#define NWAVES (NBLOCKS * WAVES_PER_BLOCK)   // 8192 waves
#define ROWS_PER_WAVE (B_ROWS / NWAVES)      // 8 rows per wave

typedef float v4f __attribute__((ext_vector_type(4)));

// ROUND-3 WINNER, stage 1 byte-identical (94.3us; ~6.0 TB/s effective).
// DO NOT TOUCH THIS KERNEL'S SOURCE: rounds 4-8 proved that ANY change
// (fused ticket tail, __launch_bounds__ occupancy forcing, waves_per_eu,
// inline-asm load pinning) re-rolls codegen and lands at 1.1-2.5 TB/s
// (187-240us). Round 8's all-L3-resident dispatch at 235us proved the
// regressions are internal issue/latency structure, not DRAM BW, and are
// not fixable by forcing MLP. This exact source is the known-good roll.
__global__ __launch_bounds__(256) void mnl_rows_kernel(
    const float* __restrict__ x,
    const float* __restrict__ y,
    const float* __restrict__ u,
    float* __restrict__ partial) {
  const int wave = threadIdx.x >> 6;
  const int lane = threadIdx.x & 63;
  const int gwave = blockIdx.x * WAVES_PER_BLOCK + wave;
  const long long row0 = (long long)gwave * ROWS_PER_WAVE;
  const float u0 = u[0];

  const v4f* __restrict__ xb = (const v4f*)x;
  const v4f* __restrict__ yb = (const v4f*)y;

  float se[ROWS_PER_WAVE], sxy[ROWS_PER_WAVE];
  unsigned choice_mask = 0;

  v4f cx[4], cy[4], nx[4], ny[4];

  // prologue: row 0 (nontemporal: streamed once)
  {
    const v4f* xr = xb + row0 * (C_COLS / 4) + lane;
    const v4f* yr = yb + row0 * (C_COLS / 4) + lane;
#pragma unroll
    for (int i = 0; i < 4; ++i) {
      cx[i] = __builtin_nontemporal_load(xr + 64 * i);
      cy[i] = __builtin_nontemporal_load(yr + 64 * i);
    }
  }

#pragma unroll
  for (int r = 0; r < ROWS_PER_WAVE; ++r) {
    if (r + 1 < ROWS_PER_WAVE) {   // prefetch next row
      const v4f* xr = xb + (row0 + r + 1) * (C_COLS / 4) + lane;
      const v4f* yr = yb + (row0 + r + 1) * (C_COLS / 4) + lane;
#pragma unroll
      for (int i = 0; i < 4; ++i) {
        nx[i] = __builtin_nontemporal_load(xr + 64 * i);
        ny[i] = __builtin_nontemporal_load(yr + 64 * i);
      }
    }

    float se_l = 0.f, sxy_l = 0.f, sy_l = 0.f;
#pragma unroll
    for (int i = 0; i < 4; ++i) {
      se_l  += __expf(cx[i].x) + __expf(cx[i].y) +
               __expf(cx[i].z) + __expf(cx[i].w);
      sxy_l += cx[i].x * cy[i].x + cx[i].y * cy[i].y +
               cx[i].z * cy[i].z + cx[i].w * cy[i].w;
      sy_l  += cy[i].x + cy[i].y + cy[i].z + cy[i].w;
    }
    se[r] = se_l;
    sxy[r] = sxy_l;
    choice_mask |= (__any(sy_l > 0.f) ? 1u : 0u) << r;   // one ballot

#pragma unroll
    for (int i = 0; i < 4; ++i) { cx[i] = nx[i]; cy[i] = ny[i]; }
  }

  // Batched butterflies: 8 rows x 2 vars interleaved -> 16 independent DS
  // ops per step, 6 steps. No serial per-row reduction bubbles.
#pragma unroll
  for (int off = 1; off < 64; off <<= 1) {
#pragma unroll
    for (int r = 0; r < ROWS_PER_WAVE; ++r) {
      se[r]  += __shfl_xor(se[r],  off, 64);
      sxy[r] += __shfl_xor(sxy[r], off, 64);
    }
  }

  // 8 independent transcendental tails (ILP), result uniform across lanes.
  float acc = 0.f;
#pragma unroll
  for (int r = 0; r < ROWS_PER_WAVE; ++r) {
    const float lse = __logf(se[r]);                             // logsumexp
    const float a = fmaxf(u0, lse);
    const float logden = a + log1pf(__expf(-fabsf(u0 - lse)));   // logaddexp
    const float s = ((choice_mask >> r) & 1u) ? sxy[r] : u0;
    acc += s - logden;
  }

  __shared__ float sh[WAVES_PER_BLOCK];
  if (lane == 0) sh[wave] = acc;
  __syncthreads();
  if (threadIdx.x == 0)
    partial[blockIdx.x] = sh[0] + sh[1] + sh[2] + sh[3];   // 1 per block
}

// Stage 2: separate kernel (independent codegen — safe to edit). Leaner than
// round 3: 2048 floats read as 512 v4f (2 per thread) instead of 8 scalar
// grid-stride reads; one butterfly + LDS combine; one store.
__global__ __launch_bounds__(256) void mnl_reduce_kernel(
    const float* __restrict__ partial, float* __restrict__ out) {
  const v4f* __restrict__ p4 = (const v4f*)partial;   // 512 v4f
  v4f a = p4[threadIdx.x];
  v4f b = p4[threadIdx.x + 256];
  float acc = (a.x + a.y + a.z + a.w) + (b.x + b.y + b.z + b.w);
#pragma unroll
  for (int off = 1; off < 64; off <<= 1) acc += __shfl_xor(acc, off, 64);

  __shared__ float sh[4];
  const int wave = threadIdx.x >> 6;
  const int lane = threadIdx.x & 63;
  if (lane == 0) sh[wave] = acc;
  __syncthreads();
  if (threadIdx.x == 0) {
    const float t = sh[0] + sh[1] + sh[2] + sh[3];
    const float scale = 1.0f / (2.302585092994046f * (float)B_ROWS);
    out[0] = -t * scale;   // -mean( (s - logden)/ln10 )
  }
}

extern "C" void kernel_launch(void* const* d_in, const int* in_sizes, int n_in,
                              void* d_out, int out_size, void* d_ws, size_t ws_size,
                              hipStream_t stream) {
  const float* x = (const float*)d_in[0];
  const float* y = (const float*)d_in[1];
  const float* u = (const float*)d_in[2];
  float* out = (float*)d_out;
  float* partial = (float*)d_ws;   // 2048 * 4 = 8 KiB scratch

  mnl_rows_kernel<<<NBLOCKS, 256, 0, stream>>>(x, y, u, partial);
  mnl_reduce_kernel<<<1, 256, 0, stream>>>(partial, out);
}